// Round 13
// baseline (115.163 us; speedup 1.0000x reference)
//
#include <hip/hip_runtime.h>

#define NBPB 128   // batches per block
#define RS   16    // ring slots (power of 2)
#define PD   12    // producer lookahead (batches); 2*PD loads in flight

static __device__ __forceinline__ unsigned umax2(unsigned a, unsigned b) { return a > b ? a : b; }

// Quad-lane broadcast via DPP quad_perm (VALU pipe). sel compile-time.
static __device__ __forceinline__ float qb(float v, int sel) {
    int i = __float_as_int(v), r;
    switch (sel) {
        case 0:  r = __builtin_amdgcn_update_dpp(0, i, 0x00, 0xF, 0xF, true); break;
        case 1:  r = __builtin_amdgcn_update_dpp(0, i, 0x55, 0xF, 0xF, true); break;
        case 2:  r = __builtin_amdgcn_update_dpp(0, i, 0xAA, 0xF, 0xF, true); break;
        default: r = __builtin_amdgcn_update_dpp(0, i, 0xFF, 0xF, 0xF, true); break;
    }
    return __int_as_float(r);
}

static __device__ __forceinline__ int mbcnt64(unsigned long long m, int acc) {
    acc = __builtin_amdgcn_mbcnt_lo((unsigned)m, acc);
    acc = __builtin_amdgcn_mbcnt_hi((unsigned)(m >> 32), acc);
    return acc;
}

// async global->LDS, 16B/lane; LDS dest = uniform base + lane*16 (HW-added)
static __device__ __forceinline__ void gload16(const float* g, void* l) {
    __builtin_amdgcn_global_load_lds(
        (const __attribute__((address_space(1))) unsigned*)g,
        (__attribute__((address_space(3))) unsigned*)l, 16, 0, 0);
}

// ---------------------------------------------------------------------------
// Producer/consumer kernel. Block = 4 waves: wave 3 streams cfg into a
// 16-slot x 2KB LDS ring with counted vmcnt (24 loads always in flight);
// waves 0-2 consume: ballot from LDS -> idx, free slot fast, then gather +
// pivot-free DPP-GE per 8-batch group. Decouples HBM duty from compute
// phases (fix for the measured lockstep: ~60us main vs 43us memory floor).
// ---------------------------------------------------------------------------
__global__ __launch_bounds__(256) void slater_pc(
    const float* __restrict__ cfg,
    const float* __restrict__ sup,
    const float* __restrict__ sdn,
    float* __restrict__ out,
    unsigned* __restrict__ ws_count,
    unsigned* __restrict__ ws_rec,
    unsigned cap)
{
    __shared__ __align__(16) unsigned char ring[RS][2048];
    __shared__ int idx_scr[3][8][2][16];
    __shared__ int readyf[RS];
    __shared__ int freef[RS];

    const int tid  = threadIdx.x;
    const int wave = tid >> 6;
    const int lane = tid & 63;
    const int b0   = blockIdx.x * NBPB;

    if (tid < RS) { readyf[tid] = 0; freef[tid] = 0; }
    __syncthreads();

    volatile int* vready = readyf;
    volatile int* vfree  = freef;

    if (wave == 3) {
        // ------------------------- producer --------------------------------
        // prologue: batches 0..PD-1 into slots 0..PD-1 (gen 0, free==0 holds)
        for (int s = 0; s < PD; ++s) {
            const float* g = cfg + (size_t)(b0 + s) * 512 + (size_t)lane * 4;
            gload16(g,       &ring[s][0]);
            gload16(g + 256, &ring[s][1024]);
        }
        for (int s = 0; s < NBPB; ++s) {
            const int t = s + PD;
            if (t < NBPB) {
                const int k = t & (RS - 1), gen = t >> 4;     // RS == 16
                while (vfree[k] != gen) __builtin_amdgcn_s_sleep(2);
                const float* g = cfg + (size_t)(b0 + t) * 512 + (size_t)lane * 4;
                gload16(g,       &ring[k][0]);
                gload16(g + 256, &ring[k][1024]);
                // retire batch s's 2 loads (<=24 younger loads outstanding)
                asm volatile("s_waitcnt vmcnt(24)" ::: "memory");
            } else {
                asm volatile("s_waitcnt vmcnt(0)" ::: "memory");
            }
            if (lane == 0) vready[s & (RS - 1)] = s + 1;
        }
    } else {
        // ------------------------- consumers -------------------------------
        const int g = lane >> 2;
        const int q = lane & 3;
        const float* tab = (g & 1) ? sdn : sup;

        for (int grp = wave; grp < NBPB / 8; grp += 3) {
            // ---- ballot 8 batches out of the ring ----
            for (int j = 0; j < 8; ++j) {
                const int b = grp * 8 + j, k = b & (RS - 1);
                while (vready[k] != b + 1) __builtin_amdgcn_s_sleep(2);
                __builtin_amdgcn_sched_barrier(0);
#pragma unroll
                for (int h = 0; h < 2; ++h) {
                    float4 v = *(const float4*)&ring[k][h * 1024 + lane * 16];
                    bool n0 = v.x != 0.f, n1 = v.y != 0.f, n2 = v.z != 0.f, n3 = v.w != 0.f;
                    unsigned long long m0 = __ballot(n0);
                    unsigned long long m1 = __ballot(n1);
                    unsigned long long m2 = __ballot(n2);
                    unsigned long long m3 = __ballot(n3);
                    int r = mbcnt64(m3, mbcnt64(m2, mbcnt64(m1, mbcnt64(m0, 0))));
                    int pos = lane * 4;
                    if (n0) idx_scr[wave][j][h][r] = pos;      // exactly 16 ones
                    r += n0;
                    if (n1) idx_scr[wave][j][h][r] = pos + 1;
                    r += n1;
                    if (n2) idx_scr[wave][j][h][r] = pos + 2;
                    r += n2;
                    if (n3) idx_scr[wave][j][h][r] = pos + 3;
                }
                asm volatile("s_waitcnt lgkmcnt(0)" ::: "memory");
                if (lane == 0) vfree[k] = (b >> 4) + 1;        // release slot
            }

            // ---- gather rows (L1-hot tables) ----
            const int4 ri = *(const int4*)&idx_scr[wave][g >> 1][g & 1][q * 4];
            const int rid[4] = {ri.x, ri.y, ri.z, ri.w};
            float rr[4][16];
#pragma unroll
            for (int j = 0; j < 4; ++j) {
                const float* p = tab + (size_t)rid[j] * 16;
                float4 a = *(const float4*)(p + 0);
                float4 b = *(const float4*)(p + 4);
                float4 e = *(const float4*)(p + 8);
                float4 f = *(const float4*)(p + 12);
                rr[j][0]=a.x;  rr[j][1]=a.y;  rr[j][2]=a.z;  rr[j][3]=a.w;
                rr[j][4]=b.x;  rr[j][5]=b.y;  rr[j][6]=b.z;  rr[j][7]=b.w;
                rr[j][8]=e.x;  rr[j][9]=e.y;  rr[j][10]=e.z; rr[j][11]=e.w;
                rr[j][12]=f.x; rr[j][13]=f.y; rr[j][14]=f.z; rr[j][15]=f.w;
            }

            // ---- pivot-free GE with DPP broadcasts ----
            float det = 1.f;
            float minpiv = 1.f;
#pragma unroll
            for (int k = 0; k < 16; ++k) {
                const int sel = k >> 2;
                const int jp  = k & 3;
                float piv = qb(rr[jp][k], sel);
                det *= piv;
                minpiv = fminf(minpiv, fabsf(piv));
                float inv = __builtin_amdgcn_rcpf(piv);
                float f0 = rr[0][k] * inv;
                float f1 = rr[1][k] * inv;
                float f2 = rr[2][k] * inv;
                float f3 = rr[3][k] * inv;
#pragma unroll
                for (int cc = k + 1; cc < 16; ++cc) {
                    float pcc = qb(rr[jp][cc], sel);
                    rr[0][cc] = __builtin_fmaf(-f0, pcc, rr[0][cc]);
                    rr[1][cc] = __builtin_fmaf(-f1, pcc, rr[1][cc]);
                    rr[2][cc] = __builtin_fmaf(-f2, pcc, rr[2][cc]);
                    rr[3][cc] = __builtin_fmaf(-f3, pcc, rr[3][cc]);
                }
            }
            bool bad = minpiv < 1e-4f;

            // ---- enqueue bad batches for pivoted cleanup ----
            int badflag = bad ? 1 : 0;
            int partnerbad = __shfl_xor(badflag, 4);
            if ((badflag | partnerbad) && (lane & 7) == 0) {
                unsigned slot = atomicAdd(ws_count, 1u);
                if (slot < cap) {
                    unsigned* rec = ws_rec + slot * 12;
                    const int j = lane >> 3;               // batch within group
                    rec[0] = (unsigned)(b0 + grp * 8 + j);
#pragma unroll
                    for (int t = 0; t < 4; ++t) {
                        const int* iu = &idx_scr[wave][j][0][t * 4];
                        const int* id = &idx_scr[wave][j][1][t * 4];
                        rec[1 + t] = (unsigned)iu[0] | ((unsigned)iu[1] << 8)
                                   | ((unsigned)iu[2] << 16) | ((unsigned)iu[3] << 24);
                        rec[5 + t] = (unsigned)id[0] | ((unsigned)id[1] << 8)
                                   | ((unsigned)id[2] << 16) | ((unsigned)id[3] << 24);
                    }
                }
            }

            // ---- combine up*down and write ----
            float prod = det * __shfl_xor(det, 4);
            if ((lane & 7) == 0) out[b0 + grp * 8 + (lane >> 3)] = prod;
        }
    }
}

// ---------------------------------------------------------------------------
// Cleanup kernel: 8 lanes per batch, full partial pivoting. Rare (~0.1%).
// ---------------------------------------------------------------------------
__global__ __launch_bounds__(256) void slater_det_cleanup(
    const float* __restrict__ sup,
    const float* __restrict__ sdn,
    float* __restrict__ out,
    const unsigned* __restrict__ ws_count,
    const unsigned* __restrict__ ws_rec,
    unsigned cap)
{
    unsigned n = *ws_count;
    if (n > cap) n = cap;
    const int tid  = blockIdx.x * 256 + threadIdx.x;
    const int unit = tid >> 3;
    const int nunits = (int)(gridDim.x * 256) >> 3;
    const int l8   = threadIdx.x & 7;
    const int wl   = threadIdx.x & 63;
    const int q    = wl & 3;
    const int gbase = wl & ~3;

    for (unsigned item = unit; item < n; item += nunits) {
        const unsigned* rec = ws_rec + item * 12;
        const unsigned batch = rec[0];
        const int half = l8 >> 2;
        const unsigned pk = rec[1 + half * 4 + q];
        const int rid[4] = { (int)(pk & 255u), (int)((pk >> 8) & 255u),
                             (int)((pk >> 16) & 255u), (int)(pk >> 24) };
        const float* tab = half ? sdn : sup;

        float rr[4][16];
#pragma unroll
        for (int j = 0; j < 4; ++j) {
            const float* p = tab + (size_t)rid[j] * 16;
            float4 a = *(const float4*)(p + 0);
            float4 b = *(const float4*)(p + 4);
            float4 e = *(const float4*)(p + 8);
            float4 f = *(const float4*)(p + 12);
            rr[j][0]=a.x;  rr[j][1]=a.y;  rr[j][2]=a.z;  rr[j][3]=a.w;
            rr[j][4]=b.x;  rr[j][5]=b.y;  rr[j][6]=b.z;  rr[j][7]=b.w;
            rr[j][8]=e.x;  rr[j][9]=e.y;  rr[j][10]=e.z; rr[j][11]=e.w;
            rr[j][12]=f.x; rr[j][13]=f.y; rr[j][14]=f.z; rr[j][15]=f.w;
        }

        unsigned am = 0xFu;
        float fdet = 1.f;
        int flips = 0;
#pragma unroll
        for (int k = 0; k < 16; ++k) {
            unsigned a0 = (__float_as_uint(rr[0][k]) & 0x7FFFFFF0u) | (unsigned)(q*4+0);
            unsigned a1 = (__float_as_uint(rr[1][k]) & 0x7FFFFFF0u) | (unsigned)(q*4+1);
            unsigned a2 = (__float_as_uint(rr[2][k]) & 0x7FFFFFF0u) | (unsigned)(q*4+2);
            unsigned a3 = (__float_as_uint(rr[3][k]) & 0x7FFFFFF0u) | (unsigned)(q*4+3);
            unsigned key0 = (am & 1u) ? a0 : (unsigned)(q*4+0);
            unsigned key1 = (am & 2u) ? a1 : (unsigned)(q*4+1);
            unsigned key2 = (am & 4u) ? a2 : (unsigned)(q*4+2);
            unsigned key3 = (am & 8u) ? a3 : (unsigned)(q*4+3);
            unsigned kloc = umax2(umax2(key0, key1), umax2(key2, key3));
            int jloc = (int)(kloc & 3u);
            float crow[16];
#pragma unroll
            for (int cc = k; cc < 16; ++cc) {
                float t01 = (jloc & 1) ? rr[1][cc] : rr[0][cc];
                float t23 = (jloc & 1) ? rr[3][cc] : rr[2][cc];
                crow[cc] = (jloc & 2) ? t23 : t01;
            }
            unsigned ko = kloc;
            ko = umax2(ko, (unsigned)__shfl_xor((int)ko, 1));
            ko = umax2(ko, (unsigned)__shfl_xor((int)ko, 2));
            int p   = (int)(ko & 15u);
            int src = gbase | (p >> 2);
            float prow[16];
#pragma unroll
            for (int cc = k; cc < 16; ++cc) prow[cc] = __shfl(crow[cc], src);
            float piv = prow[k];
            fdet *= piv;
            int t = p - q * 4;
            unsigned mlt = (t <= 0) ? 0u : ((t >= 4) ? 0xFu : ((1u << t) - 1u));
            int cnt = __popc(am & mlt);
            cnt += __shfl_xor(cnt, 1);
            cnt += __shfl_xor(cnt, 2);
            flips += cnt;
            if (q == (p >> 2)) am &= ~(1u << (p & 3));
            float inv = 1.0f / piv;
            float f0 = rr[0][k] * inv;
            float f1 = rr[1][k] * inv;
            float f2 = rr[2][k] * inv;
            float f3 = rr[3][k] * inv;
#pragma unroll
            for (int cc = k + 1; cc < 16; ++cc) {
                rr[0][cc] = __builtin_fmaf(-f0, prow[cc], rr[0][cc]);
                rr[1][cc] = __builtin_fmaf(-f1, prow[cc], rr[1][cc]);
                rr[2][cc] = __builtin_fmaf(-f2, prow[cc], rr[2][cc]);
                rr[3][cc] = __builtin_fmaf(-f3, prow[cc], rr[3][cc]);
            }
        }
        float det = (flips & 1) ? -fdet : fdet;
        float prod = det * __shfl_xor(det, 4);
        if (l8 == 0) out[batch] = prod;
    }
}

extern "C" void kernel_launch(void* const* d_in, const int* in_sizes, int n_in,
                              void* d_out, int out_size, void* d_ws, size_t ws_size,
                              hipStream_t stream) {
    const float* cfg = (const float*)d_in[0];
    const float* sup = (const float*)d_in[1];
    const float* sdn = (const float*)d_in[2];
    float* outp = (float*)d_out;
    unsigned* ws_count = (unsigned*)d_ws;
    unsigned* ws_rec   = (unsigned*)d_ws + 4;            // records at +16B
    unsigned cap = (unsigned)((ws_size - 16) / 48);      // 12 uints per record
    const int B = in_sizes[0] / 512;                     // 131072
    const int blocks = B / NBPB;                         // 1024

    hipMemsetAsync(d_ws, 0, 16, stream);
    slater_pc<<<blocks, 256, 0, stream>>>(cfg, sup, sdn, outp,
                                          ws_count, ws_rec, cap);
    slater_det_cleanup<<<16, 256, 0, stream>>>(sup, sdn, outp,
                                               ws_count, ws_rec, cap);
}